// Round 2
// baseline (379.756 us; speedup 1.0000x reference)
//
#include <hip/hip_runtime.h>
#include <stdint.h>

#define BATCH 16384
#define KDIM  512
#define NDIM  1024
#define NW    16            // 512 bits = 16 uint32 words per row
#define ROWS_PER_BLOCK 16   // 1024 blocks
#define PHASE_ROWS 8        // rows packed+consumed per barrier phase

// --- G packing, permuted to match the ballot layout of the main kernel ---
// Word m (0..15) of a packed K-row, bit c (0..31), corresponds to
//   k = 256*(m>>3) + 128*((m>>2)&1) + 4*c + (m&3)
// (h = m>>3 selects the wave half-pair, half = (m>>2)&1 selects ballot lo/hi,
//  j = m&3 selects the float4 component).
// Gt[m * NDIM + n] packs G[k, n] in that layout.
__global__ __launch_bounds__(256) void pack_g_kernel(const float* __restrict__ G,
                                                     uint32_t* __restrict__ Gt) {
    int t = blockIdx.x * 256 + threadIdx.x;   // 16384 threads: t = m*NDIM + n
    int n = t & (NDIM - 1);
    int m = t >> 10;
    int kbase = 256 * (m >> 3) + 128 * ((m >> 2) & 1) + (m & 3);
    uint32_t w = 0;
#pragma unroll
    for (int c = 0; c < 32; ++c) {
        w |= (uint32_t)(G[(size_t)(kbase + 4 * c) * NDIM + n] > 0.5f) << c;
    }
    Gt[t] = w;
}

// --- fused pack(x) + GF(2) GEMM ---
// Block: 256 threads (4 waves), handles ROWS_PER_BLOCK rows x all NDIM cols.
// Per phase: 8 rows of x are read as contiguous float4 (once, coalesced),
// bit-packed via __ballot into LDS; then each thread computes 4 columns per
// row: out = popc(XOR_m (xrow[m] & g[m])) & 1.
__global__ __launch_bounds__(256, 4) void gf2_fused_kernel(const float* __restrict__ x,
                                                           const uint32_t* __restrict__ Gt,
                                                           int* __restrict__ out) {
    const int tid = threadIdx.x;
    const int wv  = tid >> 6;        // wave id 0..3
    const int l   = tid & 63;        // lane
    const int w2  = wv >> 1;         // row parity group
    const int h   = wv & 1;          // half-row (k 0..255 vs 256..511)
    const int row0 = blockIdx.x * ROWS_PER_BLOCK;

    // g fragments: 4 columns per thread (n = c*256 + tid), 16 words each
    uint32_t g[4][16];
#pragma unroll
    for (int c = 0; c < 4; ++c) {
#pragma unroll
        for (int m = 0; m < NW; ++m) {
            g[c][m] = Gt[m * NDIM + c * 256 + tid];
        }
    }

    __shared__ __align__(16) uint32_t xw[PHASE_ROWS][NW];   // 512 B
    const float4* xf = reinterpret_cast<const float4*>(x);

    // prefetch phase-0 x data (contiguous per load instruction: 4 KB each)
    float4 f0, f1, f2, f3;
    {
        size_t base4 = (size_t)row0 * (KDIM / 4);
        f0 = xf[base4 + 0 * 256 + tid];
        f1 = xf[base4 + 1 * 256 + tid];
        f2 = xf[base4 + 2 * 256 + tid];
        f3 = xf[base4 + 3 * 256 + tid];
    }

    for (int p = 0; p < ROWS_PER_BLOCK / PHASE_ROWS; ++p) {
        const int prow0 = row0 + p * PHASE_ROWS;

        // ---- Phase A: ballot-pack 8 rows into LDS ----
        uint64_t b00 = __ballot(f0.x > 0.5f), b01 = __ballot(f0.y > 0.5f);
        uint64_t b02 = __ballot(f0.z > 0.5f), b03 = __ballot(f0.w > 0.5f);
        uint64_t b10 = __ballot(f1.x > 0.5f), b11 = __ballot(f1.y > 0.5f);
        uint64_t b12 = __ballot(f1.z > 0.5f), b13 = __ballot(f1.w > 0.5f);
        uint64_t b20 = __ballot(f2.x > 0.5f), b21 = __ballot(f2.y > 0.5f);
        uint64_t b22 = __ballot(f2.z > 0.5f), b23 = __ballot(f2.w > 0.5f);
        uint64_t b30 = __ballot(f3.x > 0.5f), b31 = __ballot(f3.y > 0.5f);
        uint64_t b32 = __ballot(f3.z > 0.5f), b33 = __ballot(f3.w > 0.5f);

        // prefetch next phase's x while ballots settle (before the barrier)
        if (p + 1 < ROWS_PER_BLOCK / PHASE_ROWS) {
            size_t base4 = (size_t)(prow0 + PHASE_ROWS) * (KDIM / 4);
            f0 = xf[base4 + 0 * 256 + tid];
            f1 = xf[base4 + 1 * 256 + tid];
            f2 = xf[base4 + 2 * 256 + tid];
            f3 = xf[base4 + 3 * 256 + tid];
        }

        if (l == 0) {
            // wave wv produced, for load q: row (2q + w2), words h*8 + {j, 4+j}
#define PUT(q, j, bq)                                                   \
            xw[2 * (q) + w2][h * 8 + (j)]     = (uint32_t)(bq);         \
            xw[2 * (q) + w2][h * 8 + 4 + (j)] = (uint32_t)((bq) >> 32);
            PUT(0, 0, b00) PUT(0, 1, b01) PUT(0, 2, b02) PUT(0, 3, b03)
            PUT(1, 0, b10) PUT(1, 1, b11) PUT(1, 2, b12) PUT(1, 3, b13)
            PUT(2, 0, b20) PUT(2, 1, b21) PUT(2, 2, b22) PUT(2, 3, b23)
            PUT(3, 0, b30) PUT(3, 1, b31) PUT(3, 2, b32) PUT(3, 3, b33)
#undef PUT
        }
        __syncthreads();

        // ---- Phase B: each thread computes 4 columns for each of 8 rows ----
#pragma unroll 2
        for (int r = 0; r < PHASE_ROWS; ++r) {
            const uint4* xr4 = reinterpret_cast<const uint4*>(&xw[r][0]);
            uint4 xa = xr4[0], xb = xr4[1], xc = xr4[2], xd = xr4[3];
            size_t obase = (size_t)(prow0 + r) * NDIM + tid;
#pragma unroll
            for (int c = 0; c < 4; ++c) {
                uint32_t t = (xa.x & g[c][0])  ^ (xa.y & g[c][1])
                           ^ (xa.z & g[c][2])  ^ (xa.w & g[c][3])
                           ^ (xb.x & g[c][4])  ^ (xb.y & g[c][5])
                           ^ (xb.z & g[c][6])  ^ (xb.w & g[c][7])
                           ^ (xc.x & g[c][8])  ^ (xc.y & g[c][9])
                           ^ (xc.z & g[c][10]) ^ (xc.w & g[c][11])
                           ^ (xd.x & g[c][12]) ^ (xd.y & g[c][13])
                           ^ (xd.z & g[c][14]) ^ (xd.w & g[c][15]);
                out[obase + c * 256] = (int)(__popc(t) & 1u);
            }
        }
        __syncthreads();   // protect xw before next phase's writes
    }
}

extern "C" void kernel_launch(void* const* d_in, const int* in_sizes, int n_in,
                              void* d_out, int out_size, void* d_ws, size_t ws_size,
                              hipStream_t stream) {
    const float* x = (const float*)d_in[0];   // [BATCH, KDIM] float32 (0/1)
    const float* G = (const float*)d_in[1];   // [KDIM, NDIM] float32 (0/1)
    int* out = (int*)d_out;                   // [BATCH, NDIM] int32

    uint32_t* Gt = (uint32_t*)d_ws;           // 64 KiB packed G

    pack_g_kernel<<<(NW * NDIM) / 256, 256, 0, stream>>>(G, Gt);
    gf2_fused_kernel<<<BATCH / ROWS_PER_BLOCK, 256, 0, stream>>>(x, Gt, out);
}

// Round 3
// 27.274 us; speedup vs baseline: 13.9236x; 13.9236x over previous
//
#include <hip/hip_runtime.h>
#include <stdint.h>

#define BATCH 16384
#define KDIM  512
#define NDIM  1024
#define NW    16            // 512 bits = 16 uint32 words per row
#define ROWS_PER_BLOCK 32   // 512 blocks, 2 blocks/CU at 16 waves each
#define PHASE_ROWS 8        // rows packed+consumed per barrier phase
#define NPHASE (ROWS_PER_BLOCK / PHASE_ROWS)

// --- G packing (UNCHANGED from round 2 — verified correct) ---
// Word m (0..15) of a packed K-row, bit c (0..31), corresponds to
//   k = 256*(m>>3) + 128*((m>>2)&1) + 4*c + (m&3)
// matching the fused kernel's ballot layout (h = wave&1 selects k-half,
// hb = ballot hi/lo 32, j = float4 component, c = lane&31).
__global__ __launch_bounds__(256) void pack_g_kernel(const float* __restrict__ G,
                                                     uint32_t* __restrict__ Gt) {
    int t = blockIdx.x * 256 + threadIdx.x;   // 16384 threads: t = m*NDIM + n
    int n = t & (NDIM - 1);
    int m = t >> 10;
    int kbase = 256 * (m >> 3) + 128 * ((m >> 2) & 1) + (m & 3);
    uint32_t w = 0;
#pragma unroll
    for (int c = 0; c < 32; ++c) {
        w |= (uint32_t)(G[(size_t)(kbase + 4 * c) * NDIM + n] > 0.5f) << c;
    }
    Gt[t] = w;
}

// --- fused pack(x) + GF(2) GEMM, low-register version ---
// 1024 threads (16 waves). Each thread owns ONE column n = tid: g[16] = 16 VGPRs.
// Per phase: one float4 load/thread covers 8 rows; wave w (q = w>>1, h = w&1)
// ballots its 256 floats of row q into 8 words; lane 0 writes them to LDS.
// Compute: out[b, n] = popc( XOR_m (xrow[m] & g[m]) ) & 1.
__global__ __launch_bounds__(1024, 8)
void gf2_fused_kernel(const float* __restrict__ x,
                      const uint32_t* __restrict__ Gt,
                      int* __restrict__ out) {
    const int tid = threadIdx.x;
    const int w   = tid >> 6;     // wave 0..15
    const int l   = tid & 63;     // lane
    const int q   = w >> 1;       // row within phase (0..7)
    const int h   = w & 1;        // k-half (0: k<256, 1: k>=256)
    const int row0 = blockIdx.x * ROWS_PER_BLOCK;

    // persistent column fragment: 16 VGPRs
    uint32_t g[NW];
#pragma unroll
    for (int m = 0; m < NW; ++m) g[m] = Gt[m * NDIM + tid];

    __shared__ __align__(16) uint32_t xw[2][PHASE_ROWS][NW];   // 2 x 512 B

    const float4* xf = reinterpret_cast<const float4*>(x);
    float4 f = xf[(size_t)row0 * (KDIM / 4) + tid];            // phase-0 slab

    for (int p = 0; p < NPHASE; ++p) {
        // ---- ballot-pack 8 rows (consumes f) ----
        uint64_t b0 = __ballot(f.x > 0.5f);
        uint64_t b1 = __ballot(f.y > 0.5f);
        uint64_t b2 = __ballot(f.z > 0.5f);
        uint64_t b3 = __ballot(f.w > 0.5f);

        // prefetch next phase's slab (hidden under compute below)
        if (p + 1 < NPHASE)
            f = xf[(size_t)(row0 + (p + 1) * PHASE_ROWS) * (KDIM / 4) + tid];

        if (l == 0) {
            uint32_t* dst = &xw[p & 1][q][h * 8];
            dst[0] = (uint32_t)b0;  dst[4] = (uint32_t)(b0 >> 32);
            dst[1] = (uint32_t)b1;  dst[5] = (uint32_t)(b1 >> 32);
            dst[2] = (uint32_t)b2;  dst[6] = (uint32_t)(b2 >> 32);
            dst[3] = (uint32_t)b3;  dst[7] = (uint32_t)(b3 >> 32);
        }
        __syncthreads();   // double-buffer: one barrier per phase is race-free

        // ---- compute 8 rows x 1 column ----
        size_t obase = (size_t)(row0 + p * PHASE_ROWS) * NDIM + tid;
#pragma unroll
        for (int r = 0; r < PHASE_ROWS; ++r) {
            const uint4* x4 = reinterpret_cast<const uint4*>(&xw[p & 1][r][0]);
            uint4 a = x4[0];      // LDS broadcast reads (uniform address)
            uint32_t t = (a.x & g[0])  ^ (a.y & g[1])  ^ (a.z & g[2])  ^ (a.w & g[3]);
            a = x4[1];
            t ^= (a.x & g[4])  ^ (a.y & g[5])  ^ (a.z & g[6])  ^ (a.w & g[7]);
            a = x4[2];
            t ^= (a.x & g[8])  ^ (a.y & g[9])  ^ (a.z & g[10]) ^ (a.w & g[11]);
            a = x4[3];
            t ^= (a.x & g[12]) ^ (a.y & g[13]) ^ (a.z & g[14]) ^ (a.w & g[15]);
            out[obase + (size_t)r * NDIM] = (int)(__popc(t) & 1u);
        }
    }
}

extern "C" void kernel_launch(void* const* d_in, const int* in_sizes, int n_in,
                              void* d_out, int out_size, void* d_ws, size_t ws_size,
                              hipStream_t stream) {
    const float* x = (const float*)d_in[0];   // [BATCH, KDIM] float32 (0/1)
    const float* G = (const float*)d_in[1];   // [KDIM, NDIM] float32 (0/1)
    int* out = (int*)d_out;                   // [BATCH, NDIM] int32

    uint32_t* Gt = (uint32_t*)d_ws;           // 64 KiB packed G

    pack_g_kernel<<<(NW * NDIM) / 256, 256, 0, stream>>>(G, Gt);
    gf2_fused_kernel<<<BATCH / ROWS_PER_BLOCK, 1024, 0, stream>>>(x, Gt, out);
}